// Round 5
// baseline (162.853 us; speedup 1.0000x reference)
//
#include <hip/hip_runtime.h>
#include <hip/hip_bf16.h>

// out[b,m,o] = sum_i x[b,m,i] * w[m,i,o] + bias[m,o]
// B=4096, M=8, IN=OUT=512, fp32. Per-mode GEMM via bf16 MFMA, fp32 accum.
// Round 5: A never touches LDS (wave-private 32-row slices, global->reg->cvt->MFMA);
// LDS holds only packed-W B tiles (2x8KB dbuf) via global_load_lds with COUNTED
// vmcnt (prefetch stays in flight across barriers). Issue-order pinned by fences.

#define B_   4096
#define M_   8
#define IN_  512
#define OUT_ 512
#define BK   32
#define NKT  16
#define WS_NEED (M_ * 4 * 16 * 8192)   // 4 MiB packed W chunks

typedef __attribute__((ext_vector_type(8))) short  short8;   // 8 bf16
typedef __attribute__((ext_vector_type(4))) float  f32x4;
typedef __attribute__((ext_vector_type(4))) int    i32x4;

#define GLB(p)  ((const __attribute__((address_space(1))) void*)(p))
#define LDSP(p) ((__attribute__((address_space(3))) void*)(p))
#define FENCE() asm volatile("" ::: "memory")

// two floats -> two RNE bf16 in one u32 (lo in low 16) — compiler emits v_cvt_pk_bf16_f32
static __device__ inline unsigned f2bf2(float lo, float hi) {
  float2 f2; f2.x = lo; f2.y = hi;
  __hip_bfloat162 h = __float22bfloat162_rn(f2);
  union { __hip_bfloat162 h; unsigned u; } c; c.h = h;
  return c.u;
}

union pk8 { i32x4 i; short8 s; };

static __device__ inline short8 cvt8(f32x4 a, f32x4 b) {
  pk8 p;
  p.i[0] = f2bf2(a[0], a[1]); p.i[1] = f2bf2(a[2], a[3]);
  p.i[2] = f2bf2(b[0], b[1]); p.i[3] = f2bf2(b[2], b[3]);
  return p.s;
}

// ---------------------------------------------------------------------------
// Prepass: W[m][i][o] f32 -> bf16 pre-swizzled tile-linear 8KB chunks in ws.
// Chunk c=(m*4+nb)*16+kb: logical (col 0..127, k 0..31) at
// phys16 = (col*64 + (k>>3)*16) ^ ((col&7)<<4).   (verified rounds 2-4)
// ---------------------------------------------------------------------------
extern "C" __global__ __launch_bounds__(256, 2)
void prep_w(const float* __restrict__ W, unsigned char* __restrict__ ws) {
  const int c  = blockIdx.x;          // 0..511
  const int kb = c & 15;
  const int nbm = c >> 4;
  const int nb = nbm & 3;
  const int m  = nbm >> 2;

  __shared__ float tile[32][132];

  const int t = threadIdx.x;
  {
    const int k  = t >> 3;
    const int n4 = (t & 7) * 16;
    const float* src = W + (size_t)m * (IN_ * OUT_) + (size_t)(kb * 32 + k) * OUT_ + nb * 128 + n4;
#pragma unroll
    for (int i = 0; i < 4; ++i) {
      f32x4 v = *(const f32x4*)(src + i * 4);
      tile[k][n4 + i * 4 + 0] = v[0];
      tile[k][n4 + i * 4 + 1] = v[1];
      tile[k][n4 + i * 4 + 2] = v[2];
      tile[k][n4 + i * 4 + 3] = v[3];
    }
  }
  __syncthreads();

  unsigned char* out = ws + (size_t)c * 8192;
#pragma unroll
  for (int s = t; s < 512; s += 256) {
    const int col = s >> 2;
    const int k8  = s & 3;
    float f[8];
#pragma unroll
    for (int j = 0; j < 8; ++j) f[j] = tile[k8 * 8 + j][col];
    i32x4 p;
    p[0] = f2bf2(f[0], f[1]); p[1] = f2bf2(f[2], f[3]);
    p[2] = f2bf2(f[4], f[5]); p[3] = f2bf2(f[6], f[7]);
    const int phys = (col * 64 + k8 * 16) ^ ((col & 7) << 4);
    *(i32x4*)(out + phys) = p;
  }
}

// ---------------------------------------------------------------------------
// Main kernel. 4 waves, each owns 32 rows x 128 cols (2x8 16x16x32 frags).
// LDS: B only, 2 x 8KB double-buffer.
// Pipeline (per-wave vmcnt queues hand-simulated; max 10 in flight):
//   prologue: issue B0(2 gload_lds), A0(4 ld), A1(4 ld); cvt A0; vmcnt(4); barrier
//   iter k:   issue B(k+1)->bufB[(k+1)&1]; issue A(k+2)->slot[k&1];
//             ds_read bf <- bufB[k&1]; MFMA x16 (af[k&1]);
//             cvt slot[(k+1)&1] -> af[(k+1)&1]  (compiler auto-waits A(k+1));
//             vmcnt(4) [tail: 0] retires B(k+1); lgkmcnt(0); barrier
// ---------------------------------------------------------------------------
extern "C" __global__ __launch_bounds__(256, 3)
void mmlin_main(const float* __restrict__ X, const unsigned char* __restrict__ Wp,
                const float* __restrict__ Bias, float* __restrict__ O) {
  __shared__ unsigned char ldsB[16384];

  const int t = threadIdx.x, l = t & 63, w = t >> 6;
  const int b0 = blockIdx.x * 128;
  const int nb = blockIdx.y;
  const int n0 = nb * 128;
  const int m  = blockIdx.z;
  const int fr = l & 15, g = l >> 4;

  // A: wave-private rows. aptr[mi] -> A[row = b0 + w*32 + mi*16 + fr][k = g*8 ...]
  const float* aptr[2];
#pragma unroll
  for (int mi = 0; mi < 2; ++mi)
    aptr[mi] = X + (size_t)(b0 + w * 32 + mi * 16 + fr) * (M_ * IN_) + m * IN_ + g * 8;

  // B staging: wave w copies bytes [w*2048, w*2048+2048) of each 8KB chunk.
  const unsigned char* b_src = Wp + (size_t)((m * 4 + nb) * 16) * 8192 + w * 2048 + l * 16;
  const int b_dst = w * 2048 + l * 16;

  // B fragment read offsets (swizzle verified rounds 2-4)
  int boff[8];
#pragma unroll
  for (int ni = 0; ni < 8; ++ni) {
    const int col = ni * 16 + fr;
    boff[ni] = (col * 64 + g * 16) ^ ((col & 7) << 4);
  }

  f32x4 acc[2][8] = {};
  f32x4 slot[2][4];      // staged fp32 A tiles (indices fold under full unroll)
  short8 af[2][2];       // converted bf16 A frags

  // ---- prologue
  FENCE();
  __builtin_amdgcn_global_load_lds(GLB(b_src),        LDSP(ldsB + b_dst),        16, 0, 0);
  __builtin_amdgcn_global_load_lds(GLB(b_src + 1024), LDSP(ldsB + b_dst + 1024), 16, 0, 0);
  FENCE();
#pragma unroll
  for (int mi = 0; mi < 2; ++mi) {
    slot[0][mi * 2 + 0] = *(const f32x4*)(aptr[mi] + 0);
    slot[0][mi * 2 + 1] = *(const f32x4*)(aptr[mi] + 4);
  }
  FENCE();
#pragma unroll
  for (int mi = 0; mi < 2; ++mi) {
    slot[1][mi * 2 + 0] = *(const f32x4*)(aptr[mi] + BK + 0);
    slot[1][mi * 2 + 1] = *(const f32x4*)(aptr[mi] + BK + 4);
  }
  FENCE();
  af[0][0] = cvt8(slot[0][0], slot[0][1]);   // auto-wait retires B0+A0
  af[0][1] = cvt8(slot[0][2], slot[0][3]);
  asm volatile("s_waitcnt vmcnt(4)" ::: "memory");  // B0 certified pre-barrier
  asm volatile("s_waitcnt lgkmcnt(0)" ::: "memory");
  __builtin_amdgcn_s_barrier();
  __builtin_amdgcn_sched_barrier(0);

#pragma unroll
  for (int k = 0; k < NKT; ++k) {
    // issue next B tile (depth 1, L2-hot), then A tile k+2 (depth 2)
    if (k + 1 < NKT) {
      FENCE();
      const unsigned char* bs = b_src + (size_t)(k + 1) * 8192;
      const int bd = ((k + 1) & 1) * 8192 + b_dst;
      __builtin_amdgcn_global_load_lds(GLB(bs),        LDSP(ldsB + bd),        16, 0, 0);
      __builtin_amdgcn_global_load_lds(GLB(bs + 1024), LDSP(ldsB + bd + 1024), 16, 0, 0);
    }
    if (k + 2 < NKT) {
      FENCE();
#pragma unroll
      for (int mi = 0; mi < 2; ++mi) {
        slot[k & 1][mi * 2 + 0] = *(const f32x4*)(aptr[mi] + (k + 2) * BK + 0);
        slot[k & 1][mi * 2 + 1] = *(const f32x4*)(aptr[mi] + (k + 2) * BK + 4);
      }
    }
    FENCE();

    // compute tile k
    const unsigned char* Bbuf = ldsB + (k & 1) * 8192;
    short8 bf0[4], bf1[4];
#pragma unroll
    for (int j = 0; j < 4; ++j) bf0[j] = *(const short8*)(Bbuf + boff[j]);
#pragma unroll
    for (int mi = 0; mi < 2; ++mi)
#pragma unroll
      for (int j = 0; j < 4; ++j)
        acc[mi][j] = __builtin_amdgcn_mfma_f32_16x16x32_bf16(
            af[k & 1][mi], bf0[j], acc[mi][j], 0, 0, 0);
#pragma unroll
    for (int j = 0; j < 4; ++j) bf1[j] = *(const short8*)(Bbuf + boff[4 + j]);
#pragma unroll
    for (int mi = 0; mi < 2; ++mi)
#pragma unroll
      for (int j = 0; j < 4; ++j)
        acc[mi][4 + j] = __builtin_amdgcn_mfma_f32_16x16x32_bf16(
            af[k & 1][mi], bf1[j], acc[mi][4 + j], 0, 0, 0);

    if (k + 1 < NKT) {
      // convert A(k+1) (compiler auto-waits its loads; leaves B(k+1)+A(k+2) in flight)
      af[(k + 1) & 1][0] = cvt8(slot[(k + 1) & 1][0], slot[(k + 1) & 1][1]);
      af[(k + 1) & 1][1] = cvt8(slot[(k + 1) & 1][2], slot[(k + 1) & 1][3]);
      if (k <= NKT - 3) { asm volatile("s_waitcnt vmcnt(4)" ::: "memory"); }
      else              { asm volatile("s_waitcnt vmcnt(0)" ::: "memory"); }
      asm volatile("s_waitcnt lgkmcnt(0)" ::: "memory");
      __builtin_amdgcn_s_barrier();
      __builtin_amdgcn_sched_barrier(0);
    }
  }

  // ---- epilogue: D frag col = fr, row = g*4 + r
#pragma unroll
  for (int ni = 0; ni < 8; ++ni) {
    const int col = n0 + ni * 16 + fr;
    const float bs = Bias[m * OUT_ + col];
#pragma unroll
    for (int mi = 0; mi < 2; ++mi) {
#pragma unroll
      for (int r = 0; r < 4; ++r) {
        const int row = b0 + w * 32 + mi * 16 + g * 4 + r;
        O[(size_t)row * (M_ * OUT_) + m * OUT_ + col] = acc[mi][ni][r] + bs;
      }
    }
  }
}

// ---------------------------------------------------------------------------
// Fallback (round-3 kernel, verified) if ws too small.
// ---------------------------------------------------------------------------
extern "C" __global__ __launch_bounds__(256, 2)
void mmlin_fallback(const float* __restrict__ X, const float* __restrict__ W,
                    const float* __restrict__ Bias, float* __restrict__ O) {
  __shared__ unsigned char lds[16384];
  const int t = threadIdx.x;
  const int lane = t & 63;
  const int w = t >> 6;
  const int b0 = blockIdx.x * 128;
  const int n0 = blockIdx.y * 128;
  const int m  = blockIdx.z;

  const int ar  = t >> 1;
  const int ac0 = (t & 1) * 16;
  const float* aptr = X + (size_t)(b0 + ar) * (M_ * IN_) + m * IN_ + ac0;
  const int swzA  = (ar & 7) << 4;
  const int a_st0 = (ar * 64 + ac0 * 2)      ^ swzA;
  const int a_st1 = (ar * 64 + ac0 * 2 + 16) ^ swzA;

  const int bc  = t & 127;
  const int bk0 = (t >> 7) * 16;
  const float* bptr = W + (size_t)m * IN_ * OUT_ + (size_t)bk0 * OUT_ + n0 + bc;
  const int swzB  = (bc & 7) << 4;
  const int b_st0 = (8192 + bc * 64 + bk0 * 2)      ^ swzB;
  const int b_st1 = (8192 + bc * 64 + bk0 * 2 + 16) ^ swzB;

  const int wr = (w >> 1) * 64, wc = (w & 1) * 64;
  const int fr = lane & 15;
  const int fkB = (lane >> 4) * 16;

  int a_ld[4], b_ld[4];
#pragma unroll
  for (int mi = 0; mi < 4; ++mi) {
    int row = wr + mi * 16 + fr;
    a_ld[mi] = (row * 64 + fkB) ^ ((row & 7) << 4);
  }
#pragma unroll
  for (int ni = 0; ni < 4; ++ni) {
    int col = wc + ni * 16 + fr;
    b_ld[ni] = (8192 + col * 64 + fkB) ^ ((col & 7) << 4);
  }

  f32x4 acc[4][4] = {};
  f32x4 a_raw[4];
  float b_raw[16];
  {
    const f32x4* ap = (const f32x4*)aptr;
#pragma unroll
    for (int i = 0; i < 4; ++i) a_raw[i] = ap[i];
#pragma unroll
    for (int j = 0; j < 16; ++j) b_raw[j] = bptr[(size_t)j * OUT_];
  }
  i32x4 apk0, apk1, bpk0, bpk1;
  apk0[0] = f2bf2(a_raw[0][0], a_raw[0][1]); apk0[1] = f2bf2(a_raw[0][2], a_raw[0][3]);
  apk0[2] = f2bf2(a_raw[1][0], a_raw[1][1]); apk0[3] = f2bf2(a_raw[1][2], a_raw[1][3]);
  apk1[0] = f2bf2(a_raw[2][0], a_raw[2][1]); apk1[1] = f2bf2(a_raw[2][2], a_raw[2][3]);
  apk1[2] = f2bf2(a_raw[3][0], a_raw[3][1]); apk1[3] = f2bf2(a_raw[3][2], a_raw[3][3]);
  bpk0[0] = f2bf2(b_raw[0],  b_raw[1]);  bpk0[1] = f2bf2(b_raw[2],  b_raw[3]);
  bpk0[2] = f2bf2(b_raw[4],  b_raw[5]);  bpk0[3] = f2bf2(b_raw[6],  b_raw[7]);
  bpk1[0] = f2bf2(b_raw[8],  b_raw[9]);  bpk1[1] = f2bf2(b_raw[10], b_raw[11]);
  bpk1[2] = f2bf2(b_raw[12], b_raw[13]); bpk1[3] = f2bf2(b_raw[14], b_raw[15]);

  for (int kk = 0; kk < IN_; kk += BK) {
    __syncthreads();
    *(i32x4*)(lds + a_st0) = apk0;
    *(i32x4*)(lds + a_st1) = apk1;
    *(i32x4*)(lds + b_st0) = bpk0;
    *(i32x4*)(lds + b_st1) = bpk1;
    __syncthreads();

    const int kn = kk + BK;
    if (kn < IN_) {
      const f32x4* ap = (const f32x4*)(aptr + kn);
#pragma unroll
      for (int i = 0; i < 4; ++i) a_raw[i] = ap[i];
#pragma unroll
      for (int j = 0; j < 16; ++j) b_raw[j] = bptr[(size_t)(kn + j) * OUT_];
    }

    short8 af[4], bf4[4];
#pragma unroll
    for (int mi = 0; mi < 4; ++mi) af[mi]  = *(const short8*)(lds + a_ld[mi]);
#pragma unroll
    for (int ni = 0; ni < 4; ++ni) bf4[ni] = *(const short8*)(lds + b_ld[ni]);

#pragma unroll
    for (int mi = 0; mi < 4; ++mi)
#pragma unroll
      for (int ni = 0; ni < 4; ++ni)
        acc[mi][ni] = __builtin_amdgcn_mfma_f32_16x16x32_bf16(
            af[mi], bf4[ni], acc[mi][ni], 0, 0, 0);

    if (kn < IN_) {
      apk0[0] = f2bf2(a_raw[0][0], a_raw[0][1]); apk0[1] = f2bf2(a_raw[0][2], a_raw[0][3]);
      apk0[2] = f2bf2(a_raw[1][0], a_raw[1][1]); apk0[3] = f2bf2(a_raw[1][2], a_raw[1][3]);
      apk1[0] = f2bf2(a_raw[2][0], a_raw[2][1]); apk1[1] = f2bf2(a_raw[2][2], a_raw[2][3]);
      apk1[2] = f2bf2(a_raw[3][0], a_raw[3][1]); apk1[3] = f2bf2(a_raw[3][2], a_raw[3][3]);
      bpk0[0] = f2bf2(b_raw[0],  b_raw[1]);  bpk0[1] = f2bf2(b_raw[2],  b_raw[3]);
      bpk0[2] = f2bf2(b_raw[4],  b_raw[5]);  bpk0[3] = f2bf2(b_raw[6],  b_raw[7]);
      bpk1[0] = f2bf2(b_raw[8],  b_raw[9]);  bpk1[1] = f2bf2(b_raw[10], b_raw[11]);
      bpk1[2] = f2bf2(b_raw[12], b_raw[13]); bpk1[3] = f2bf2(b_raw[14], b_raw[15]);
    }
  }

#pragma unroll
  for (int ni = 0; ni < 4; ++ni) {
    const int col = n0 + wc + ni * 16 + fr;
    const float bs = Bias[m * OUT_ + col];
#pragma unroll
    for (int mi = 0; mi < 4; ++mi) {
#pragma unroll
      for (int r = 0; r < 4; ++r) {
        const int row = b0 + wr + mi * 16 + (lane >> 4) * 4 + r;
        O[(size_t)row * (M_ * OUT_) + m * OUT_ + col] = acc[mi][ni][r] + bs;
      }
    }
  }
}

extern "C" void kernel_launch(void* const* d_in, const int* in_sizes, int n_in,
                              void* d_out, int out_size, void* d_ws, size_t ws_size,
                              hipStream_t stream) {
  const float* X    = (const float*)d_in[0];
  const float* W    = (const float*)d_in[1];
  const float* Bias = (const float*)d_in[2];
  float* O = (float*)d_out;

  dim3 grid(B_ / 128, OUT_ / 128, M_);
  if (ws_size >= (size_t)WS_NEED) {
    prep_w<<<dim3(512), dim3(256), 0, stream>>>(W, (unsigned char*)d_ws);
    mmlin_main<<<grid, dim3(256), 0, stream>>>(X, (const unsigned char*)d_ws, Bias, O);
  } else {
    mmlin_fallback<<<grid, dim3(256), 0, stream>>>(X, W, Bias, O);
  }
}